// Round 18
// baseline (40.063 us; speedup 1.0000x reference)
//
#include <hip/hip_runtime.h>

// SplineConv as skinny-K GEMM: out[n,oi] = sum_k W[n,k] * CT[k,oi].
// M=32768 points, N=1024 channels, K=64. f16 MFMA 16x16x32, f32 acc.
//
// Round-18: SINGLE fused kernel (R17's two-kernel structure carried ~5-8us of
// overhead: prep launch + serialization + 4MiB Wp write + 4MiB cross-XCD read).
//  - Phase 1 (threads 0-127): per-point spline weights -> dense 64-wide W row
//    emitted as 8 f16x8 chunks DIRECTLY in MFMA B-fragment layout into LDS
//    wrec[chunk][point] (16 KB; lane-contiguous 16B writes, conflict-free).
//    Same weight math as the verified R13-17 prep (absmax 1.95e-3).
//  - Phase 1b: A-fragments straight from C (L2-hot 200KB; one-time scalar
//    loads + f16 cvt). ONE __syncthreads after phase 1. Main loop has NO
//    global loads: B-frags = 2 x ds_read_b128/tile (uniform-bank floor).
//  - Loop (8 point-tiles): 8 MFMAs -> wave-private XOR-swizzled LDS transpose
//    (no barriers) -> 4 plain f32x4 stores (4x256B segments = full 128B
//    lines/instr), byte-identical to R17's store path.

#define NPTS   32768
#define DIM    1024

typedef _Float16 f16x8 __attribute__((ext_vector_type(8)));
typedef float    f32x4 __attribute__((ext_vector_type(4)));

__device__ __forceinline__ float safe_div(float n, float d) {
    return (d == 0.0f) ? n : (n / d);
}

__device__ __forceinline__ void span_weights(float v, const float* __restrict__ T,
                                             int& k, float& w0, float& w1, float& w2) {
    float t3 = T[3], t4 = T[4], t5 = T[5], t6 = T[6];
    k = 2 + (v >= t3) + (v >= t4) + (v >= t5) + (v >= t6);
    float Tm1 = T[k - 1], T0 = T[k], Tp1 = T[k + 1], Tp2 = T[k + 2];
    float a10 = safe_div(v - Tm1, Tp1 - Tm1);
    float a11 = safe_div(v - T0,  Tp2 - T0);
    float a21 = safe_div(v - T0,  Tp1 - T0);
    w0 = (1.0f - a21) * (1.0f - a10);
    w1 = (1.0f - a21) * a10 + a21 * (1.0f - a11);
    w2 = a21 * a11;
}

__global__ __launch_bounds__(256, 4) void spline_fused_kernel(
    const float* __restrict__ C,
    const float* __restrict__ xy,
    const float* __restrict__ Tx,
    const float* __restrict__ Ty,
    float* __restrict__ out)
{
    __shared__ _Float16 wrec[8][128][8];   // [k-chunk][point][8 f16] = 16 KB
    __shared__ float    tbuf[4][1024];     // wave-private transpose, 16 KB

    const int t      = threadIdx.x;
    const int lane   = t & 63;
    const int w      = t >> 6;             // wave 0..3
    const int chgrp  = blockIdx.x & 3;     // 256-channel group
    const int pchunk = blockIdx.x >> 2;    // 128-point chunk

    // --- Phase 1: threads 0-127 expand their point's weights into dense
    // 64-wide W row, written as 8 fragment chunks (chunk c = step*4+g holds
    // k = 32*(c>>2) + 8*(c&3) + j). Lane-contiguous 16B LDS writes. ---
    if (t < 128) {
        const int p = pchunk * 128 + t;
        const float2 pt2 = ((const float2*)xy)[p];
        int kx, ky;
        float wx0, wx1, wx2, wy0, wy1, wy2;
        span_weights(pt2.x, Tx, kx, wx0, wx1, wx2);
        span_weights(pt2.y, Ty, ky, wy0, wy1, wy2);
        const int off = (kx - 2) * 7 + (ky - 2);
#pragma unroll
        for (int c = 0; c < 8; ++c) {
            f16x8 frag;
#pragma unroll
            for (int j = 0; j < 8; ++j) {
                const int k   = 32 * (c >> 2) + 8 * (c & 3) + j;
                const int rel = k - off;
                const float va = (rel >= 14) ? wx2 : ((rel >= 7) ? wx1 : wx0);
                const int   bb = rel - ((rel >= 14) ? 14 : ((rel >= 7) ? 7 : 0));
                const float vb = (bb == 0) ? wy0 : ((bb == 1) ? wy1 : wy2);
                const bool valid = (rel >= 0) && (rel <= 16) && (bb >= 0) && (bb <= 2);
                frag[j] = (_Float16)(valid ? va * vb : 0.0f);
            }
            *(f16x8*)&wrec[c][t][0] = frag;
        }
    }

    // --- Phase 1b: A-fragments straight from C (row=ch=lane%16 of tile,
    // k=(lane/16)*8+st*32+j; k>=49 -> 0). One-time, L2-hot. ---
    f16x8 af[4][2];
    {
        const int colch = lane & 15;
        const int g     = lane >> 4;
#pragma unroll
        for (int ct = 0; ct < 4; ++ct) {
            const int ch = (chgrp * 16 + w * 4 + ct) * 16 + colch;
            const float* crow = C + (size_t)ch * 49;
#pragma unroll
            for (int st = 0; st < 2; ++st) {
                f16x8 frag;
#pragma unroll
                for (int j = 0; j < 8; ++j) {
                    const int k = st * 32 + g * 8 + j;
                    frag[j] = (_Float16)((k < 49) ? crow[k] : 0.0f);
                }
                af[ct][st] = frag;
            }
        }
    }

    __syncthreads();   // records visible to all waves (only barrier)

    const int p  = lane & 15;              // D col = point within tile
    const int h  = lane >> 4;              // D row group / k-group
    const int cb = lane & 15;              // read-back granule index
    float* const wbuf = &tbuf[w][0];

#pragma unroll
    for (int pt = 0; pt < 8; ++pt) {
        const int ptile = pchunk * 8 + pt;

        // B-fragments from LDS: chunk = h (step0) / 4+h (step1), point = pt*16+p.
        const f16x8 b0 = *(const f16x8*)&wrec[h][pt * 16 + p][0];
        const f16x8 b1 = *(const f16x8*)&wrec[4 + h][pt * 16 + p][0];

        f32x4 acc[4];
#pragma unroll
        for (int ct = 0; ct < 4; ++ct) {
            f32x4 z; z[0] = 0.0f; z[1] = 0.0f; z[2] = 0.0f; z[3] = 0.0f;
            acc[ct] = __builtin_amdgcn_mfma_f32_16x16x32_f16(af[ct][0], b0, z, 0, 0, 0);
        }
#pragma unroll
        for (int ct = 0; ct < 4; ++ct)
            acc[ct] = __builtin_amdgcn_mfma_f32_16x16x32_f16(af[ct][1], b1, acc[ct], 0, 0, 0);

        // --- Wave-private LDS transpose (no barrier), XOR granule swizzle. ---
#pragma unroll
        for (int ct = 0; ct < 4; ++ct) {
            const int g16 = ct * 4 + h;
            const int col = (g16 & 8) | ((g16 ^ p) & 7);
            *(f32x4*)(wbuf + p * 64 + (col << 2)) = acc[ct];
        }

        // --- Store: instr gg covers points gg*4..gg*4+3 as 4 x 256B contiguous
        // segments (full 128B lines). Plain write-back f32x4. ---
#pragma unroll
        for (int gg = 0; gg < 4; ++gg) {
            const int pr  = gg * 4 + h;
            const int col = (cb & 8) | ((cb ^ pr) & 7);
            f32x4 v = *(const f32x4*)(wbuf + pr * 64 + (col << 2));
            float* dst = out + (size_t)(ptile * 16 + pr) * DIM
                             + chgrp * 256 + w * 64 + cb * 4;
            *(f32x4*)dst = v;
        }
    }
}

extern "C" void kernel_launch(void* const* d_in, const int* in_sizes, int n_in,
                              void* d_out, int out_size, void* d_ws, size_t ws_size,
                              hipStream_t stream) {
    const float* xy = (const float*)d_in[0];
    const float* Tx = (const float*)d_in[1];
    const float* Ty = (const float*)d_in[2];
    const float* C  = (const float*)d_in[3];
    float* out = (float*)d_out;

    spline_fused_kernel<<<4 * (NPTS / 128), 256, 0, stream>>>(C, xy, Tx, Ty, out);
}

// Round 19
// 34.086 us; speedup vs baseline: 1.1754x; 1.1754x over previous
//
#include <hip/hip_runtime.h>

// SplineConv as skinny-K GEMM: out[n,oi] = sum_k W[n,k] * CT[k,oi].
// M=32768 points, N=1024 channels, K=64. f16 MFMA 16x16x32, f32 acc.
//
// Round-19 = round-15 (best, 36.9us) + ONE change: XCD-aware blockIdx swizzle.
// Default mapping round-robins consecutive blocks across the 8 XCDs -> each
// XCD writes 1KiB fragments at 4KiB stride scattered over 128MiB. Remap
// swz = (bid&7)*128 + (bid>>3) (bijective, 1024=8x128): each XCD owns a
// contiguous run of 32 pchunks -> sequential 16MiB write stream per XCD
// (fill-kernel DRAM page locality; T1, measured +10-12% when HBM-bound).
//  - Everything else identical to R15: block-level LDS transpose (double
//    buffer, 1 barrier/iter), nt stores of 64-lane x 16B = 1KiB full lines,
//    XOR swizzle (ci ^ ((p&7)<<2)), prep kernel verified (absmax 1.95e-3).

#define NPTS   32768
#define DIM    1024
#define MT     (NPTS / 16)        // 2048 point-tiles
#define WELEM  (MT * 2 * 64 * 8)  // W_perm f16 elements (4 MiB)

typedef _Float16 f16x8 __attribute__((ext_vector_type(8)));
typedef float    f32x4 __attribute__((ext_vector_type(4)));

__device__ __forceinline__ float safe_div(float n, float d) {
    return (d == 0.0f) ? n : (n / d);
}

__device__ __forceinline__ void span_weights(float v, const float* __restrict__ T,
                                             int& k, float& w0, float& w1, float& w2) {
    float t3 = T[3], t4 = T[4], t5 = T[5], t6 = T[6];
    k = 2 + (v >= t3) + (v >= t4) + (v >= t5) + (v >= t6);
    float Tm1 = T[k - 1], T0 = T[k], Tp1 = T[k + 1], Tp2 = T[k + 2];
    float a10 = safe_div(v - Tm1, Tp1 - Tm1);
    float a11 = safe_div(v - T0,  Tp2 - T0);
    float a21 = safe_div(v - T0,  Tp1 - T0);
    w0 = (1.0f - a21) * (1.0f - a10);
    w1 = (1.0f - a21) * a10 + a21 * (1.0f - a11);
    w2 = a21 * a11;
}

__global__ __launch_bounds__(256) void prep_kernel(
    const float* __restrict__ xy,
    const float* __restrict__ Tx,
    const float* __restrict__ Ty,
    const float* __restrict__ C,
    _Float16* __restrict__ Wp,
    _Float16* __restrict__ Cp)
{
    const int b = blockIdx.x;
    const int t = threadIdx.x;
    if (b < MT / 2) {
        // ---- W_perm: one thread per (point-tile, k-step, lane) 16B record ----
        const int id   = b * 256 + t;          // 0 .. 262143
        const int lane = id & 63;
        const int step = (id >> 6) & 1;
        const int tile = id >> 7;
        const int n    = tile * 16 + (lane & 15);   // B col = lane%16
        const int g    = lane >> 4;                  // k-group

        const float2 pt = ((const float2*)xy)[n];
        int kx, ky;
        float wx0, wx1, wx2, wy0, wy1, wy2;
        span_weights(pt.x, Tx, kx, wx0, wx1, wx2);
        span_weights(pt.y, Ty, ky, wy0, wy1, wy2);
        const int off = (kx - 2) * 7 + (ky - 2);

        f16x8 frag;
#pragma unroll
        for (int j = 0; j < 8; ++j) {
            const int k   = step * 32 + g * 8 + j;
            const int rel = k - off;
            const float va = (rel >= 14) ? wx2 : ((rel >= 7) ? wx1 : wx0);
            const int   bb = rel - ((rel >= 14) ? 14 : ((rel >= 7) ? 7 : 0));
            const float vb = (bb == 0) ? wy0 : ((bb == 1) ? wy1 : wy2);
            const bool valid = (rel >= 0) && (rel <= 16) && (bb >= 0) && (bb <= 2);
            frag[j] = (_Float16)(valid ? va * vb : 0.0f);
        }
        *(f16x8*)(Wp + (size_t)id * 8) = frag;
    } else if (b < MT / 2 + 32) {
        // ---- C_perm: C[ch][k] in A-fragment order (row=ch, k-grouped) ----
        const int id    = (b - MT / 2) * 256 + t;   // 0 .. 8191
        const int lane  = id & 63;
        const int step  = (id >> 6) & 1;
        const int ctile = id >> 7;
        const int ch    = ctile * 16 + (lane & 15); // A row = lane%16
        const int g     = lane >> 4;

        f16x8 frag;
#pragma unroll
        for (int j = 0; j < 8; ++j) {
            const int k = step * 32 + g * 8 + j;
            frag[j] = (_Float16)((k < 49) ? C[(size_t)ch * 49 + k] : 0.0f);
        }
        *(f16x8*)(Cp + (size_t)id * 8) = frag;
    }
}

__global__ __launch_bounds__(256, 4) void spline_mfma_kernel(
    const _Float16* __restrict__ Wp,
    const _Float16* __restrict__ Cp,
    float* __restrict__ out)
{
    __shared__ float lds[2][16 * 256];         // 32 KiB double buffer

    const int t    = threadIdx.x;
    const int lane = t & 63;
    const int w    = t >> 6;                   // wave 0..3

    // --- T1 XCD swizzle: 1024 blocks = 8 XCDs x 128. Each XCD gets a
    // contiguous run of 32 pchunks -> sequential 16 MiB output stream. ---
    const int bid    = blockIdx.x;
    const int swz    = ((bid & 7) << 7) | (bid >> 3);
    const int chgrp  = swz & 3;                // 256-channel group
    const int pchunk = swz >> 2;               // 8 point-tile chunk (128 points)

    // A-fragments: this wave's 4 channel-tiles x 2 k-steps (register-resident;
    // Cp is 128 KiB -> L2-hot for every block).
    f16x8 af[4][2];
#pragma unroll
    for (int ct = 0; ct < 4; ++ct)
#pragma unroll
        for (int st = 0; st < 2; ++st) {
            const int ctg = chgrp * 16 + w * 4 + ct;
            af[ct][st] = *(const f16x8*)(Cp + ((size_t)(ctg * 2 + st) * 64 + lane) * 8);
        }

    const int p = lane & 15;                   // D col = point within tile
    const int h = lane >> 4;                   // D row group

#pragma unroll
    for (int pt = 0; pt < 8; ++pt) {
        const int ptile = pchunk * 8 + pt;
        const f16x8 b0 = *(const f16x8*)(Wp + ((size_t)(ptile * 2 + 0) * 64 + lane) * 8);
        const f16x8 b1 = *(const f16x8*)(Wp + ((size_t)(ptile * 2 + 1) * 64 + lane) * 8);

        f32x4 acc[4];
#pragma unroll
        for (int ct = 0; ct < 4; ++ct) {
            f32x4 z; z[0] = 0.0f; z[1] = 0.0f; z[2] = 0.0f; z[3] = 0.0f;
            acc[ct] = __builtin_amdgcn_mfma_f32_16x16x32_f16(af[ct][0], b0, z, 0, 0, 0);
        }
#pragma unroll
        for (int ct = 0; ct < 4; ++ct)
            acc[ct] = __builtin_amdgcn_mfma_f32_16x16x32_f16(af[ct][1], b1, acc[ct], 0, 0, 0);

        // --- LDS transpose: acc[ct] = channels (w*64 + ct*16 + h*4 .. +4) of
        // point p, within this block's 256-channel slice. XOR-swizzled. ---
        float* buf = lds[pt & 1];
#pragma unroll
        for (int ct = 0; ct < 4; ++ct) {
            const int ci = w * 64 + ct * 16 + h * 4;
            *(f32x4*)(buf + p * 256 + (ci ^ ((p & 7) << 2))) = acc[ct];
        }
        __syncthreads();

        // --- Cooperative store: wave w emits points 4w..4w+3, each as one
        // 64-lane x 16B contiguous 1KiB full-line nontemporal store. ---
#pragma unroll
        for (int r = 0; r < 4; ++r) {
            const int pr = 4 * w + r;
            const int ci = lane * 4;
            f32x4 v = *(const f32x4*)(buf + pr * 256 + (ci ^ ((pr & 7) << 2)));
            float* dst = out + (size_t)(ptile * 16 + pr) * DIM + chgrp * 256 + ci;
            __builtin_nontemporal_store(v, (f32x4*)dst);
        }
        // Double buffer: next iter writes lds[(pt+1)&1]; slowest wave can still
        // be reading lds[pt&1] -> no second barrier needed.
    }
}

extern "C" void kernel_launch(void* const* d_in, const int* in_sizes, int n_in,
                              void* d_out, int out_size, void* d_ws, size_t ws_size,
                              hipStream_t stream) {
    const float* xy = (const float*)d_in[0];
    const float* Tx = (const float*)d_in[1];
    const float* Ty = (const float*)d_in[2];
    const float* C  = (const float*)d_in[3];
    float* out = (float*)d_out;

    _Float16* Wp = (_Float16*)d_ws;            // 4 MiB
    _Float16* Cp = Wp + WELEM;                 // 128 KiB

    prep_kernel<<<MT / 2 + 32, 256, 0, stream>>>(xy, Tx, Ty, C, Wp, Cp);
    spline_mfma_kernel<<<4 * (MT / 8), 256, 0, stream>>>(Wp, Cp, out);
}

// Round 20
// 34.029 us; speedup vs baseline: 1.1773x; 1.0017x over previous
//
#include <hip/hip_runtime.h>

// SplineConv as skinny-K GEMM: out[n,oi] = sum_k W[n,k] * CT[k,oi].
// M=32768 points, N=1024 channels, K=64. f16 MFMA 16x16x32, f32 acc.
//
// Round-20 = round-19 (34.1us, XCD swizzle CONFIRMED +8%) + R16's barrier-free
// wave-private transpose. R16 alone was flat because pre-swizzle the scattered
// XCD write traffic masked the barrier cost (regime gating); with locality
// fixed, the per-iter __syncthreads (hipcc emits s_waitcnt vmcnt(0) before
// s_barrier -> full store-drain x8) is the next candidate limiter.
//  - T1 XCD swizzle: swz=(bid&7)*128+(bid>>3); 4 consecutive swz on one XCD
//    cover all 1024 ch of the same 128 points = contiguous 512KB per group.
//  - Wave-private 4KiB LDS transpose, NO barriers in the whole kernel.
//  - Stores: 4 x 256B segments per instr = full 128B lines, nontemporal.
//  - Wp fragments prefetched one tile ahead.
// prep_kernel identical to R13-R19 (verified, absmax 1.95e-3).

#define NPTS   32768
#define DIM    1024
#define MT     (NPTS / 16)        // 2048 point-tiles
#define WELEM  (MT * 2 * 64 * 8)  // W_perm f16 elements (4 MiB)

typedef _Float16 f16x8 __attribute__((ext_vector_type(8)));
typedef float    f32x4 __attribute__((ext_vector_type(4)));

__device__ __forceinline__ float safe_div(float n, float d) {
    return (d == 0.0f) ? n : (n / d);
}

__device__ __forceinline__ void span_weights(float v, const float* __restrict__ T,
                                             int& k, float& w0, float& w1, float& w2) {
    float t3 = T[3], t4 = T[4], t5 = T[5], t6 = T[6];
    k = 2 + (v >= t3) + (v >= t4) + (v >= t5) + (v >= t6);
    float Tm1 = T[k - 1], T0 = T[k], Tp1 = T[k + 1], Tp2 = T[k + 2];
    float a10 = safe_div(v - Tm1, Tp1 - Tm1);
    float a11 = safe_div(v - T0,  Tp2 - T0);
    float a21 = safe_div(v - T0,  Tp1 - T0);
    w0 = (1.0f - a21) * (1.0f - a10);
    w1 = (1.0f - a21) * a10 + a21 * (1.0f - a11);
    w2 = a21 * a11;
}

__global__ __launch_bounds__(256) void prep_kernel(
    const float* __restrict__ xy,
    const float* __restrict__ Tx,
    const float* __restrict__ Ty,
    const float* __restrict__ C,
    _Float16* __restrict__ Wp,
    _Float16* __restrict__ Cp)
{
    const int b = blockIdx.x;
    const int t = threadIdx.x;
    if (b < MT / 2) {
        // ---- W_perm: one thread per (point-tile, k-step, lane) 16B record ----
        const int id   = b * 256 + t;          // 0 .. 262143
        const int lane = id & 63;
        const int step = (id >> 6) & 1;
        const int tile = id >> 7;
        const int n    = tile * 16 + (lane & 15);   // B col = lane%16
        const int g    = lane >> 4;                  // k-group

        const float2 pt = ((const float2*)xy)[n];
        int kx, ky;
        float wx0, wx1, wx2, wy0, wy1, wy2;
        span_weights(pt.x, Tx, kx, wx0, wx1, wx2);
        span_weights(pt.y, Ty, ky, wy0, wy1, wy2);
        const int off = (kx - 2) * 7 + (ky - 2);

        f16x8 frag;
#pragma unroll
        for (int j = 0; j < 8; ++j) {
            const int k   = step * 32 + g * 8 + j;
            const int rel = k - off;
            const float va = (rel >= 14) ? wx2 : ((rel >= 7) ? wx1 : wx0);
            const int   bb = rel - ((rel >= 14) ? 14 : ((rel >= 7) ? 7 : 0));
            const float vb = (bb == 0) ? wy0 : ((bb == 1) ? wy1 : wy2);
            const bool valid = (rel >= 0) && (rel <= 16) && (bb >= 0) && (bb <= 2);
            frag[j] = (_Float16)(valid ? va * vb : 0.0f);
        }
        *(f16x8*)(Wp + (size_t)id * 8) = frag;
    } else if (b < MT / 2 + 32) {
        // ---- C_perm: C[ch][k] in A-fragment order (row=ch, k-grouped) ----
        const int id    = (b - MT / 2) * 256 + t;   // 0 .. 8191
        const int lane  = id & 63;
        const int step  = (id >> 6) & 1;
        const int ctile = id >> 7;
        const int ch    = ctile * 16 + (lane & 15); // A row = lane%16
        const int g     = lane >> 4;

        f16x8 frag;
#pragma unroll
        for (int j = 0; j < 8; ++j) {
            const int k = step * 32 + g * 8 + j;
            frag[j] = (_Float16)((k < 49) ? C[(size_t)ch * 49 + k] : 0.0f);
        }
        *(f16x8*)(Cp + (size_t)id * 8) = frag;
    }
}

__global__ __launch_bounds__(256, 4) void spline_mfma_kernel(
    const _Float16* __restrict__ Wp,
    const _Float16* __restrict__ Cp,
    float* __restrict__ out)
{
    __shared__ float lds[4 * 1024];            // 4 KiB per wave, private

    const int t    = threadIdx.x;
    const int lane = t & 63;
    const int w    = t >> 6;                   // wave 0..3

    // --- T1 XCD swizzle (confirmed +8%): contiguous output per XCD. ---
    const int bid    = blockIdx.x;
    const int swz    = ((bid & 7) << 7) | (bid >> 3);
    const int chgrp  = swz & 3;                // 256-channel group
    const int pchunk = swz >> 2;               // 8 point-tile chunk (128 points)

    float* const wbuf = lds + w * 1024;        // this wave's region

    // A-fragments: this wave's 4 channel-tiles x 2 k-steps (register-resident;
    // Cp is 128 KiB -> L2-hot for every block).
    f16x8 af[4][2];
#pragma unroll
    for (int ct = 0; ct < 4; ++ct)
#pragma unroll
        for (int st = 0; st < 2; ++st) {
            const int ctg = chgrp * 16 + w * 4 + ct;
            af[ct][st] = *(const f16x8*)(Cp + ((size_t)(ctg * 2 + st) * 64 + lane) * 8);
        }

    const int p  = lane & 15;                  // D col = point within tile
    const int h  = lane >> 4;                  // D row group
    const int cb = lane & 15;                  // read-back granule index

    // Prefetch first tile's B-fragments.
    const int ptile0 = pchunk * 8;
    f16x8 nb0 = *(const f16x8*)(Wp + ((size_t)(ptile0 * 2 + 0) * 64 + lane) * 8);
    f16x8 nb1 = *(const f16x8*)(Wp + ((size_t)(ptile0 * 2 + 1) * 64 + lane) * 8);

#pragma unroll
    for (int pt = 0; pt < 8; ++pt) {
        const int ptile = pchunk * 8 + pt;
        const f16x8 b0 = nb0;
        const f16x8 b1 = nb1;
        if (pt + 1 < 8) {   // issue next tile's loads BEFORE this tile's stores
            nb0 = *(const f16x8*)(Wp + ((size_t)((ptile + 1) * 2 + 0) * 64 + lane) * 8);
            nb1 = *(const f16x8*)(Wp + ((size_t)((ptile + 1) * 2 + 1) * 64 + lane) * 8);
        }

        f32x4 acc[4];
#pragma unroll
        for (int ct = 0; ct < 4; ++ct) {
            f32x4 z; z[0] = 0.0f; z[1] = 0.0f; z[2] = 0.0f; z[3] = 0.0f;
            acc[ct] = __builtin_amdgcn_mfma_f32_16x16x32_f16(af[ct][0], b0, z, 0, 0, 0);
        }
#pragma unroll
        for (int ct = 0; ct < 4; ++ct)
            acc[ct] = __builtin_amdgcn_mfma_f32_16x16x32_f16(af[ct][1], b1, acc[ct], 0, 0, 0);

        // --- Wave-private LDS transpose (no barrier). Write: point p, granule
        // g16 = ct*4+h (channels g16*4..+3 of this wave's 64), XOR-swizzled. ---
#pragma unroll
        for (int ct = 0; ct < 4; ++ct) {
            const int g16 = ct * 4 + h;
            const int col = (g16 & 8) | ((g16 ^ p) & 7);
            *(f32x4*)(wbuf + p * 64 + (col << 2)) = acc[ct];
        }

        // --- Read back + store: instr gg covers points gg*4..gg*4+3, each as
        // 16 lanes x 16B = 256B contiguous (2 full 128B lines). ---
#pragma unroll
        for (int gg = 0; gg < 4; ++gg) {
            const int pr  = gg * 4 + h;
            const int col = (cb & 8) | ((cb ^ pr) & 7);
            f32x4 v = *(const f32x4*)(wbuf + pr * 64 + (col << 2));
            float* dst = out + (size_t)(ptile * 16 + pr) * DIM
                             + chgrp * 256 + w * 64 + cb * 4;
            __builtin_nontemporal_store(v, (f32x4*)dst);
        }
    }
}

extern "C" void kernel_launch(void* const* d_in, const int* in_sizes, int n_in,
                              void* d_out, int out_size, void* d_ws, size_t ws_size,
                              hipStream_t stream) {
    const float* xy = (const float*)d_in[0];
    const float* Tx = (const float*)d_in[1];
    const float* Ty = (const float*)d_in[2];
    const float* C  = (const float*)d_in[3];
    float* out = (float*)d_out;

    _Float16* Wp = (_Float16*)d_ws;            // 4 MiB
    _Float16* Cp = Wp + WELEM;                 // 128 KiB

    prep_kernel<<<MT / 2 + 32, 256, 0, stream>>>(xy, Tx, Ty, C, Wp, Cp);
    spline_mfma_kernel<<<4 * (MT / 8), 256, 0, stream>>>(Wp, Cp, out);
}